// Round 3
// baseline (1834552.148 us; speedup 1.0000x reference)
//
#include <hip/hip_runtime.h>
#include <cstdint>
#include <cstddef>

#define H        2048
#define T_STEPS  16384
#define G        256     // workgroups == CUs, 1 WG/CU
#define HC       8       // h indices per WG (H/G)
#define WGSIZE   256
#define NXCD     8

// ---- workspace layout (bytes); total 90176 < 128KB (proven safe size) ----
// GLOB: ull[2][1024] tagged granules {f16x2,tag} -- producers publish here (MALL)
// LOC (per XCD): u32[2][1024] untagged payloads (8KB, synced by flag)
//                + u32 flag[2][4] replicated on 128B lines (1KB)
// CNT:  ull[8] hub-election counters
#define GLOB_BYTES   16384
#define LOC_PAY_B    8192
#define LOC_STRIDE_B 9216
#define LOC_OFF_B    GLOB_BYTES
#define CNT_OFF_B    (LOC_OFF_B + NXCD * LOC_STRIDE_B)   // 90112
#define WS_BYTES     (CNT_OFF_B + NXCD * 8)              // 90176
#define WS_ULL       (WS_BYTES / 8)                      // 11272
#define LOC_STRIDE_U (LOC_STRIDE_B / 8)                  // 1152

// ---- LDS layout (bytes) ----
#define LDS_S_OFF    0                         // float2 samples[16384] = 128KB
#define LDS_H16_OFF  131072                    // uint32 h16[2][1024] packed f16x2 = 8KB
#define LDS_RED_OFF  (131072 + 8192)           // float red[8]
#define LDS_MISC_OFF (131072 + 8192 + 32)      // int misc[4] (hub flag)
#define LDS_BYTES    (131072 + 8192 + 32 + 16) // 139312 < 160KB

typedef unsigned long long ull;
typedef unsigned int uv4 __attribute__((ext_vector_type(4)));
typedef _Float16 half2_ __attribute__((ext_vector_type(2)));

__device__ __forceinline__ float sigmoidf_(float x) {
    return 1.0f / (1.0f + __expf(-x));
}
__device__ __forceinline__ float tanhf_(float x) {
    return 1.0f - 2.0f / (__expf(2.0f * x) + 1.0f);
}
__device__ __forceinline__ uint32_t pack_f16x2(float a, float b) {
    _Float16 ha = (_Float16)a, hb = (_Float16)b;
    return (uint32_t)__builtin_bit_cast(uint16_t, ha)
         | ((uint32_t)__builtin_bit_cast(uint16_t, hb) << 16);
}
__device__ __forceinline__ float f16lo(uint32_t d) {
    return (float)__builtin_bit_cast(_Float16, (uint16_t)(d & 0xFFFFu));
}
__device__ __forceinline__ float f16hi(uint32_t d) {
    return (float)__builtin_bit_cast(_Float16, (uint16_t)(d >> 16));
}
__device__ __forceinline__ float dot2f(uint32_t w, uint32_t h, float acc) {
#if __has_builtin(__builtin_amdgcn_fdot2)
    return __builtin_amdgcn_fdot2(__builtin_bit_cast(half2_, w),
                                  __builtin_bit_cast(half2_, h), acc, false);
#else
    return acc + f16lo(w) * f16lo(h) + f16hi(w) * f16hi(h);
#endif
}
// cross-XCD publish (proven in rounds 0-1)
__device__ __forceinline__ void st_agent_u64(ull* p, ull v) {
    __hip_atomic_store(p, v, __ATOMIC_RELAXED, __HIP_MEMORY_SCOPE_AGENT);
}
__device__ __forceinline__ void st_local_u32(uint32_t* p, uint32_t v) {
    __hip_atomic_store(p, v, __ATOMIC_RELAXED, __HIP_MEMORY_SCOPE_WORKGROUP);
}

__global__ void init_hrep_kernel(ull* __restrict__ hl) {
    int i = blockIdx.x * 256 + threadIdx.x;
    if (i >= WS_ULL) return;
    ull v = 0ull;
    if (i < 2048) {
        // global tagged region: parity0 = h0 tag0; parity1 = invalid tag
        v = (i < 1024) ? 0ull : 0xFFFFFFFF00000000ull;
    } else if (i < CNT_OFF_B / 8) {
        int r = (i - 2048) % LOC_STRIDE_U;
        if (r >= 1024) {                      // flag lines (128B apart)
            int m = r - 1024;
            if ((m & 15) == 0) {
                int c = m >> 4;               // flag copy idx: 0..3 p0, 4..7 p1
                v = (c < 4) ? 0ull : 0xFFFFFFFFull;   // low u32 is the flag
            }
        }
        // payload parity0 = 0 (h0) -- v already 0
    }
    __hip_atomic_store(hl + i, v, __ATOMIC_RELAXED, __HIP_MEMORY_SCOPE_AGENT);
}

extern "C" __global__ void __launch_bounds__(WGSIZE, 1)
gru_persistent_kernel(const float* __restrict__ samples,
                      const float* __restrict__ w_ih,
                      const float* __restrict__ w_hh,
                      const float* __restrict__ b_ih,
                      const float* __restrict__ b_hh,
                      const float* __restrict__ fc_w,
                      const float* __restrict__ fc_b,
                      float* __restrict__ out,
                      ull*   __restrict__ hrep)
{
    extern __shared__ char smem[];
    float2*   slds = (float2*)(smem + LDS_S_OFF);
    uint32_t* h16s = (uint32_t*)(smem + LDS_H16_OFF);
    float*    red  = (float*)(smem + LDS_RED_OFF);
    int*      misc = (int*)(smem + LDS_MISC_OFF);

    const int g    = blockIdx.x;
    const int tid  = threadIdx.x;
    const int wave = tid >> 6;
    const int lane = tid & 63;

    // ---- physical XCD id (HW-verified on MI355X: returns 0..7) ----
    uint32_t xcc;
    asm volatile("s_getreg_b32 %0, hwreg(HW_REG_XCC_ID)" : "=s"(xcc));
    xcc &= (NXCD - 1);
    if (tid == 0) {
        ull r = __hip_atomic_fetch_add(hrep + CNT_OFF_B / 8 + xcc, 1ull,
                                       __ATOMIC_RELAXED, __HIP_MEMORY_SCOPE_AGENT);
        misc[0] = (r == 0ull) ? 1 : 0;
    }

    // ---- one-time: stage this wave's 6 w_hh rows into VGPRs as f16x2 ----
    uint4 wreg[6][4];
    float4 creg[6];
#pragma unroll
    for (int qi = 0; qi < 6; ++qi) {
        const int grow = (qi >> 1) * H + g * HC + 2 * wave + (qi & 1);
        const float* wr = w_hh + (size_t)grow * H;
#pragma unroll
        for (int k = 0; k < 4; ++k) {
            const float* s2 = wr + 8 * (lane + 64 * k);
            float4 a = *(const float4*)(s2);
            float4 b = *(const float4*)(s2 + 4);
            uint4 p;
            p.x = pack_f16x2(a.x, a.y);
            p.y = pack_f16x2(a.z, a.w);
            p.z = pack_f16x2(b.x, b.y);
            p.w = pack_f16x2(b.z, b.w);
            wreg[qi][k] = p;
        }
        creg[qi] = make_float4(w_ih[grow * 2 + 0], w_ih[grow * 2 + 1],
                               b_ih[grow], b_hh[grow]);
    }
    {   // one-time: samples -> LDS
        const float4* s4 = (const float4*)samples;
        float4* d4 = (float4*)slds;
        for (int i = tid; i < T_STEPS / 2; i += WGSIZE) d4[i] = s4[i];
    }
    __syncthreads();
    const int is_hub = misc[0];
    char*     wsb  = (char*)hrep;
    uint32_t* locp = (uint32_t*)(wsb + LOC_OFF_B + (size_t)xcc * LOC_STRIDE_B);
    char*     locf = wsb + LOC_OFF_B + (size_t)xcc * LOC_STRIDE_B + LOC_PAY_B;
    const int fcpy = g & 3;   // which flag replica this WG polls

    float hloc0 = 0.0f, hloc1 = 0.0f;

    for (int t = 0; t < T_STEPS; ++t) {
        float2 sv = slds[t];
        const int p = t & 1;
        const uint32_t tu = (uint32_t)t;
        uint4 hw;

        if (is_hub) {
            // hub: poll the GLOBAL (MALL) tagged region -- only 8 WGs device-wide
            const ull* gp = hrep + ((size_t)p << 10) + tid * 4;
            uv4 q0, q1;
            for (;;) {
                asm volatile(
                    "global_load_dwordx4 %0, %2, off sc0 sc1\n\t"
                    "global_load_dwordx4 %1, %2, off offset:16 sc0 sc1\n\t"
                    "s_waitcnt vmcnt(0)"
                    : "=v"(q0), "=v"(q1)
                    : "v"(gp)
                    : "memory");
                if ((q0.y == tu) & (q0.w == tu) & (q1.y == tu) & (q1.w == tu)) break;
            }
            hw.x = q0.x; hw.y = q0.z; hw.z = q1.x; hw.w = q1.z;
            // copy untagged payload into this XCD's L2 (plain writeback store)
            *(uint4*)(locp + p * 1024 + tid * 4) = hw;
        } else {
            // reader: poll this XCD's replicated ready flag (L2-local, ~200cy)
            const uint32_t* fp =
                (const uint32_t*)(locf + (((size_t)p * 4 + fcpy) << 7));
            int ok = 0;
            for (int spin = 0; spin < 1024; ++spin) {
                uint32_t fl;
                asm volatile(
                    "global_load_dword %0, %1, off sc0\n\t"
                    "s_waitcnt vmcnt(0)"
                    : "=v"(fl)
                    : "v"(fp)
                    : "memory");
                if (fl == tu) { ok = 1; break; }
                __builtin_amdgcn_s_sleep(1);
            }
            if (ok) {
                uv4 pq;
                const uint32_t* pp = locp + p * 1024 + tid * 4;
                asm volatile(
                    "global_load_dwordx4 %0, %1, off sc0\n\t"
                    "s_waitcnt vmcnt(0)"
                    : "=v"(pq)
                    : "v"(pp)
                    : "memory");
                hw.x = pq.x; hw.y = pq.y; hw.z = pq.z; hw.w = pq.w;
            } else {
                // bounded-spin fallback: proven global tagged poll (correctness
                // guaranteed even if the local-broadcast path never works)
                const ull* gp = hrep + ((size_t)p << 10) + tid * 4;
                uv4 q0, q1;
                for (;;) {
                    asm volatile(
                        "global_load_dwordx4 %0, %2, off sc0 sc1\n\t"
                        "global_load_dwordx4 %1, %2, off offset:16 sc0 sc1\n\t"
                        "s_waitcnt vmcnt(0)"
                        : "=v"(q0), "=v"(q1)
                        : "v"(gp)
                        : "memory");
                    if ((q0.y == tu) & (q0.w == tu) & (q1.y == tu) & (q1.w == tu)) break;
                    __builtin_amdgcn_s_sleep(1);
                }
                hw.x = q0.x; hw.y = q0.z; hw.z = q1.x; hw.w = q1.z;
            }
        }

        // stage the 4 f16x2 pairs into this parity's LDS buffer
        *(uint4*)(h16s + p * 1024 + tid * 4) = hw;
        __syncthreads();   // drains LDS write AND hub's payload store (vmcnt(0))
        if (is_hub && tid < 4)
            st_local_u32((uint32_t*)(locf + (((size_t)p * 4 + tid) << 7)), tu);

        uint4 hq[4];
#pragma unroll
        for (int k = 0; k < 4; ++k) {
            if (k == wave) hq[k] = hw;
            else           hq[k] = *(const uint4*)(h16s + p * 1024 + (lane + 64 * k) * 4);
        }

        float acc[6];
#pragma unroll
        for (int qi = 0; qi < 6; ++qi) {
            float s = 0.0f;
#pragma unroll
            for (int k = 0; k < 4; ++k) {
                const uint4 wv = wreg[qi][k];
                s = dot2f(wv.x, hq[k].x, s);
                s = dot2f(wv.y, hq[k].y, s);
                s = dot2f(wv.z, hq[k].z, s);
                s = dot2f(wv.w, hq[k].w, s);
            }
            acc[qi] = s;
        }
#pragma unroll
        for (int off = 32; off > 0; off >>= 1) {
#pragma unroll
            for (int qi = 0; qi < 6; ++qi)
                acc[qi] += __shfl_xor(acc[qi], off, 64);
        }

        if (lane == 0) {
            float hn2[2];
            float hold[2] = {hloc0, hloc1};
#pragma unroll
            for (int jj = 0; jj < 2; ++jj) {
                float4 cr = creg[jj];
                float4 cz = creg[2 + jj];
                float4 cn = creg[4 + jj];
                float xr = sv.x * cr.x + sv.y * cr.y + cr.z;
                float xz = sv.x * cz.x + sv.y * cz.y + cz.z;
                float xn = sv.x * cn.x + sv.y * cn.y + cn.z;
                float r = sigmoidf_(xr + acc[jj]     + cr.w);
                float z = sigmoidf_(xz + acc[2 + jj] + cz.w);
                float n = tanhf_(xn + r * (acc[4 + jj] + cn.w));
                hn2[jj] = (1.0f - z) * n + z * hold[jj];
            }
            hloc0 = hn2[0];
            hloc1 = hn2[1];
            // publish ONE tagged granule to the single global region
            ull s0 = (ull)pack_f16x2(hn2[0], hn2[1]) | ((ull)(uint32_t)(t + 1) << 32);
            const int pn = (t + 1) & 1;
            st_agent_u64(hrep + ((size_t)pn << 10) + g * 4 + wave, s0);
        }
        // no end-of-step barrier: next step stages into the OTHER LDS parity
    }

    // ---- epilogue: WG 0 computes sigmoid(h_T . fc_w + fc_b) from GLOBAL ----
    if (g == 0) {
        const ull* lp = hrep + ((size_t)(T_STEPS & 1) << 10) + tid * 4;
        const uint32_t tu = (uint32_t)T_STEPS;
        uv4 q0, q1;
        for (;;) {
            asm volatile(
                "global_load_dwordx4 %0, %2, off sc0 sc1\n\t"
                "global_load_dwordx4 %1, %2, off offset:16 sc0 sc1\n\t"
                "s_waitcnt vmcnt(0)"
                : "=v"(q0), "=v"(q1)
                : "v"(lp)
                : "memory");
            if ((q0.y == tu) & (q0.w == tu) & (q1.y == tu) & (q1.w == tu)) break;
            __builtin_amdgcn_s_sleep(2);
        }
        float hv[8];
        hv[0] = f16lo(q0.x); hv[1] = f16hi(q0.x);
        hv[2] = f16lo(q0.z); hv[3] = f16hi(q0.z);
        hv[4] = f16lo(q1.x); hv[5] = f16hi(q1.x);
        hv[6] = f16lo(q1.z); hv[7] = f16hi(q1.z);
        float pacc = 0.0f;
#pragma unroll
        for (int e = 0; e < 8; ++e)
            pacc += hv[e] * fc_w[tid * 8 + e];
#pragma unroll
        for (int off = 32; off > 0; off >>= 1)
            pacc += __shfl_xor(pacc, off, 64);
        if (lane == 0) red[wave] = pacc;
        __syncthreads();
        if (tid == 0) {
            float s = red[0] + red[1] + red[2] + red[3];
            out[0] = sigmoidf_(s + fc_b[0]);
        }
    }
}

extern "C" void kernel_launch(void* const* d_in, const int* in_sizes, int n_in,
                              void* d_out, int out_size, void* d_ws, size_t ws_size,
                              hipStream_t stream) {
    const float* samples = (const float*)d_in[0];
    const float* w_ih    = (const float*)d_in[1];
    const float* w_hh    = (const float*)d_in[2];
    const float* b_ih    = (const float*)d_in[3];
    const float* b_hh    = (const float*)d_in[4];
    const float* fc_w    = (const float*)d_in[5];
    const float* fc_b    = (const float*)d_in[6];
    float* out  = (float*)d_out;
    ull*   hrep = (ull*)d_ws;    // 90176 B: glob + per-XCD local + counters

    hipLaunchKernelGGL(init_hrep_kernel, dim3((WS_ULL + 255) / 256), dim3(256),
                       0, stream, hrep);

    hipFuncSetAttribute((const void*)gru_persistent_kernel,
                        hipFuncAttributeMaxDynamicSharedMemorySize, LDS_BYTES);

    void* args[] = {(void*)&samples, (void*)&w_ih, (void*)&w_hh, (void*)&b_ih,
                    (void*)&b_hh, (void*)&fc_w, (void*)&fc_b,
                    (void*)&out, (void*)&hrep};
    hipError_t rc = hipLaunchCooperativeKernel(
        reinterpret_cast<void*>(gru_persistent_kernel),
        dim3(G), dim3(WGSIZE), args, LDS_BYTES, stream);
    if (rc != hipSuccess) {
        hipLaunchKernelGGL(gru_persistent_kernel, dim3(G), dim3(WGSIZE), LDS_BYTES, stream,
                           samples, w_ih, w_hh, b_ih, b_hh, fc_w, fc_b, out, hrep);
    }
}

// Round 4
// 55188.324 us; speedup vs baseline: 33.2417x; 33.2417x over previous
//
#include <hip/hip_runtime.h>
#include <cstdint>
#include <cstddef>

#define H        2048
#define T_STEPS  16384
#define G        256     // workgroups == CUs, 1 WG/CU
#define HC       8       // h indices per WG (H/G)
#define WGSIZE   256
#define NREP     8       // mailbox replicas: reader WG g polls replica g&7

// ---- LDS layout (bytes): weights in VGPRs, samples in LDS ----
#define LDS_S_OFF    0                         // float2 samples[16384] = 128KB
#define LDS_H16_OFF  131072                    // uint32 h16[2][1024] packed f16x2 = 8KB
#define LDS_RED_OFF  (131072 + 8192)           // float red[8]
#define LDS_BYTES    (131072 + 8192 + 32)      // 139296 < 160KB

typedef unsigned long long ull;
typedef unsigned int uv4 __attribute__((ext_vector_type(4)));
typedef _Float16 half2_ __attribute__((ext_vector_type(2)));

__device__ __forceinline__ float sigmoidf_(float x) {
    return 1.0f / (1.0f + __expf(-x));
}
__device__ __forceinline__ float tanhf_(float x) {
    return 1.0f - 2.0f / (__expf(2.0f * x) + 1.0f);
}
__device__ __forceinline__ uint32_t pack_f16x2(float a, float b) {
    _Float16 ha = (_Float16)a, hb = (_Float16)b;
    return (uint32_t)__builtin_bit_cast(uint16_t, ha)
         | ((uint32_t)__builtin_bit_cast(uint16_t, hb) << 16);
}
__device__ __forceinline__ float f16lo(uint32_t d) {
    return (float)__builtin_bit_cast(_Float16, (uint16_t)(d & 0xFFFFu));
}
__device__ __forceinline__ float f16hi(uint32_t d) {
    return (float)__builtin_bit_cast(_Float16, (uint16_t)(d >> 16));
}
__device__ __forceinline__ float dot2f(uint32_t w, uint32_t h, float acc) {
#if __has_builtin(__builtin_amdgcn_fdot2)
    return __builtin_amdgcn_fdot2(__builtin_bit_cast(half2_, w),
                                  __builtin_bit_cast(half2_, h), acc, false);
#else
    return acc + f16lo(w) * f16lo(h) + f16hi(w) * f16hi(h);
#endif
}

// hrep layout: [8 replicas][2 parities][1024 slots of {f16x2, u32 tag}] = 128KB
__global__ void init_hrep_kernel(ull* __restrict__ hl) {
    int i = blockIdx.x * 256 + threadIdx.x;            // 0..16383
    int parity = (i >> 10) & 1;
    // parity 0 of every replica: h=(0,0) tagged 0 (the t=0 state); parity 1: invalid.
    ull v = (parity == 0) ? 0ull : 0xFFFFFFFF00000000ull;
    __hip_atomic_store(hl + i, v, __ATOMIC_RELAXED, __HIP_MEMORY_SCOPE_AGENT);
}

extern "C" __global__ void __launch_bounds__(WGSIZE, 1)
gru_persistent_kernel(const float* __restrict__ samples,
                      const float* __restrict__ w_ih,
                      const float* __restrict__ w_hh,
                      const float* __restrict__ b_ih,
                      const float* __restrict__ b_hh,
                      const float* __restrict__ fc_w,
                      const float* __restrict__ fc_b,
                      float* __restrict__ out,
                      ull*   __restrict__ hrep)    // [8][2][1024] tagged slots
{
    extern __shared__ char smem[];
    float2*   slds = (float2*)(smem + LDS_S_OFF);      // samples, LDS-resident
    uint32_t* h16s = (uint32_t*)(smem + LDS_H16_OFF);  // [2][1024]
    float*    red  = (float*)(smem + LDS_RED_OFF);

    const int g    = blockIdx.x;
    const int tid  = threadIdx.x;
    const int wave = tid >> 6;
    const int lane = tid & 63;
    const int myrep = g & (NREP - 1);   // the replica this WG reads

    // ---- one-time: stage this wave's 6 w_hh rows into VGPRs as f16x2 ----
    uint4 wreg[6][4];
    float4 creg[6];                     // (w_ih0, w_ih1, b_ih, b_hh) per row
#pragma unroll
    for (int qi = 0; qi < 6; ++qi) {
        const int grow = (qi >> 1) * H + g * HC + 2 * wave + (qi & 1);
        const float* wr = w_hh + (size_t)grow * H;
#pragma unroll
        for (int k = 0; k < 4; ++k) {
            const float* s2 = wr + 8 * (lane + 64 * k);
            float4 a = *(const float4*)(s2);
            float4 b = *(const float4*)(s2 + 4);
            uint4 p;
            p.x = pack_f16x2(a.x, a.y);
            p.y = pack_f16x2(a.z, a.w);
            p.z = pack_f16x2(b.x, b.y);
            p.w = pack_f16x2(b.z, b.w);
            wreg[qi][k] = p;
        }
        creg[qi] = make_float4(w_ih[grow * 2 + 0], w_ih[grow * 2 + 1],
                               b_ih[grow], b_hh[grow]);
    }
    {   // one-time: samples -> LDS
        const float4* s4 = (const float4*)samples;
        float4* d4 = (float4*)slds;
        for (int i = tid; i < T_STEPS / 2; i += WGSIZE) d4[i] = s4[i];
    }
    __syncthreads();

    // publish targets: lanes 0-7 each own one replica (one atomic each,
    // issued as a single instruction across the 8 lanes)
    ull* pub_e = hrep + ((size_t)(2 * (lane & 7) + 0) << 10) + g * 4 + wave;  // pn=0
    ull* pub_o = hrep + ((size_t)(2 * (lane & 7) + 1) << 10) + g * 4 + wave;  // pn=1

    float hloc0 = 0.0f, hloc1 = 0.0f;

    for (int t = 0; t < T_STEPS; ++t) {
        float2 sv = slds[t];
        const int p = t & 1;

        // poll OUR REPLICA's 4 slots (32B) until all tags==t.  Hot spin, no
        // sleep: the vmcnt(0) stall paces the loop at load latency.
        const ull* lp = hrep + ((size_t)(myrep * 2 + p) << 10) + tid * 4;
        const uint32_t tu = (uint32_t)t;
        uv4 q0, q1;
        for (;;) {
            asm volatile(
                "global_load_dwordx4 %0, %2, off sc0 sc1\n\t"
                "global_load_dwordx4 %1, %2, off offset:16 sc0 sc1\n\t"
                "s_waitcnt vmcnt(0)"
                : "=v"(q0), "=v"(q1)
                : "v"(lp)
                : "memory");
            if ((q0.y == tu) & (q0.w == tu) & (q1.y == tu) & (q1.w == tu)) break;
        }
        // stage the 4 f16x2 pairs into this parity's LDS buffer
        uint4 hw;
        hw.x = q0.x; hw.y = q0.z; hw.z = q1.x; hw.w = q1.z;
        *(uint4*)(h16s + p * 1024 + tid * 4) = hw;
        __syncthreads();   // the only barrier: h16s[p] complete before compute

        // lane l consumes chunks {l, l+64, l+128, l+192}; own chunk from regs
        uint4 hq[4];
#pragma unroll
        for (int k = 0; k < 4; ++k) {
            if (k == wave) hq[k] = hw;
            else           hq[k] = *(const uint4*)(h16s + p * 1024 + (lane + 64 * k) * 4);
        }

        float acc[6];
#pragma unroll
        for (int qi = 0; qi < 6; ++qi) {
            float s = 0.0f;
#pragma unroll
            for (int k = 0; k < 4; ++k) {
                const uint4 wv = wreg[qi][k];
                s = dot2f(wv.x, hq[k].x, s);
                s = dot2f(wv.y, hq[k].y, s);
                s = dot2f(wv.z, hq[k].z, s);
                s = dot2f(wv.w, hq[k].w, s);
            }
            acc[qi] = s;
        }
#pragma unroll
        for (int off = 32; off > 0; off >>= 1) {
#pragma unroll
            for (int qi = 0; qi < 6; ++qi)
                acc[qi] += __shfl_xor(acc[qi], off, 64);
        }

        // gate tail split across lanes 0/1 (jj = lane); constant-index selects
        // keep everything in registers (no dynamic reg-array indexing).
        const bool l0 = (lane == 0);
        float4 cr = l0 ? creg[0] : creg[1];
        float4 cz = l0 ? creg[2] : creg[3];
        float4 cn = l0 ? creg[4] : creg[5];
        float aR = l0 ? acc[0] : acc[1];
        float aZ = l0 ? acc[2] : acc[3];
        float aN = l0 ? acc[4] : acc[5];
        float hold = l0 ? hloc0 : hloc1;
        float xr = sv.x * cr.x + sv.y * cr.y + cr.z;
        float xz = sv.x * cz.x + sv.y * cz.y + cz.z;
        float xn = sv.x * cn.x + sv.y * cn.y + cn.z;
        float r  = sigmoidf_(xr + aR + cr.w);
        float z  = sigmoidf_(xz + aZ + cz.w);
        float n  = tanhf_(xn + r * (aN + cn.w));
        float hn = (1.0f - z) * n + z * hold;    // meaningful in lanes 0,1

        float h0n = __shfl(hn, 0, 64);
        float h1n = __shfl(hn, 1, 64);
        hloc0 = h0n;
        hloc1 = h1n;

        // publish: agent-scope atomic exchange executes AT the MALL slice and
        // leaves the line MALL-resident (vs sc1 store write-around/invalidate
        // -> HBM round trip for the first reader).  8 replicas in ONE
        // instruction via lanes 0-7.
        ull s0 = (ull)pack_f16x2(h0n, h1n) | ((ull)(uint32_t)(t + 1) << 32);
        const int pn = (t + 1) & 1;
        if (lane < 8) {
            ull* pp = pn ? pub_o : pub_e;
            (void)__hip_atomic_exchange(pp, s0, __ATOMIC_RELAXED,
                                        __HIP_MEMORY_SCOPE_AGENT);
        }
        // no end-of-step barrier: next step stages into the OTHER LDS parity
    }

    // ---- epilogue: WG 0 computes sigmoid(h_T . fc_w + fc_b) ----
    if (g == 0) {
        const ull* lp = hrep + ((size_t)(T_STEPS & 1) << 10) + tid * 4;  // replica 0
        const uint32_t tu = (uint32_t)T_STEPS;
        uv4 q0, q1;
        for (;;) {
            asm volatile(
                "global_load_dwordx4 %0, %2, off sc0 sc1\n\t"
                "global_load_dwordx4 %1, %2, off offset:16 sc0 sc1\n\t"
                "s_waitcnt vmcnt(0)"
                : "=v"(q0), "=v"(q1)
                : "v"(lp)
                : "memory");
            if ((q0.y == tu) & (q0.w == tu) & (q1.y == tu) & (q1.w == tu)) break;
            __builtin_amdgcn_s_sleep(2);
        }
        float hv[8];
        hv[0] = f16lo(q0.x); hv[1] = f16hi(q0.x);
        hv[2] = f16lo(q0.z); hv[3] = f16hi(q0.z);
        hv[4] = f16lo(q1.x); hv[5] = f16hi(q1.x);
        hv[6] = f16lo(q1.z); hv[7] = f16hi(q1.z);
        float pacc = 0.0f;
#pragma unroll
        for (int e = 0; e < 8; ++e)
            pacc += hv[e] * fc_w[tid * 8 + e];
#pragma unroll
        for (int off = 32; off > 0; off >>= 1)
            pacc += __shfl_xor(pacc, off, 64);
        if (lane == 0) red[wave] = pacc;
        __syncthreads();
        if (tid == 0) {
            float s = red[0] + red[1] + red[2] + red[3];
            out[0] = sigmoidf_(s + fc_b[0]);
        }
    }
}

extern "C" void kernel_launch(void* const* d_in, const int* in_sizes, int n_in,
                              void* d_out, int out_size, void* d_ws, size_t ws_size,
                              hipStream_t stream) {
    const float* samples = (const float*)d_in[0];
    const float* w_ih    = (const float*)d_in[1];
    const float* w_hh    = (const float*)d_in[2];
    const float* b_ih    = (const float*)d_in[3];
    const float* b_hh    = (const float*)d_in[4];
    const float* fc_w    = (const float*)d_in[5];
    const float* fc_b    = (const float*)d_in[6];
    float* out  = (float*)d_out;
    ull*   hrep = (ull*)d_ws;    // [8][2][1024] tagged slots = 128KB

    // seed every replica: parity-0 = h0 (zeros, tag 0); parity-1 = sentinel
    hipLaunchKernelGGL(init_hrep_kernel, dim3(64), dim3(256), 0, stream, hrep);

    hipFuncSetAttribute((const void*)gru_persistent_kernel,
                        hipFuncAttributeMaxDynamicSharedMemorySize, LDS_BYTES);

    void* args[] = {(void*)&samples, (void*)&w_ih, (void*)&w_hh, (void*)&b_ih,
                    (void*)&b_hh, (void*)&fc_w, (void*)&fc_b,
                    (void*)&out, (void*)&hrep};
    hipError_t rc = hipLaunchCooperativeKernel(
        reinterpret_cast<void*>(gru_persistent_kernel),
        dim3(G), dim3(WGSIZE), args, LDS_BYTES, stream);
    if (rc != hipSuccess) {
        hipLaunchKernelGGL(gru_persistent_kernel, dim3(G), dim3(WGSIZE), LDS_BYTES, stream,
                           samples, w_ih, w_hh, b_ih, b_hh, fc_w, fc_b, out, hrep);
    }
}